// Round 3
// baseline (11015.956 us; speedup 1.0000x reference)
//
#include <hip/hip_runtime.h>
#include <math.h>

// ---------------------------------------------------------------------------
// NCPDecoder: 3-cell CfC RNN, B=1024, T=256.
// Round 5->6: LDS-broadcast-pipe relief via 4-col register blocking.
// R5 (8.69 ms bench / 10.3 ms prof): VALUBusy 76%, HBM 0.5%. Phase ~40 us.
// Arithmetic: FMA floor ~19k cyc/SIMD/phase, but LDS pipe (per-CU, shared)
// carried 5552 ds_read_b128/phase (4 per k4 per WAVE; broadcast reuse only
// 2 cols/thread) ~= 66.6k cyc -> LDS pipe was the pole.
// R6: 4 contiguous cols per thread (16 FMA per ds_read_b128), halving the
// matvec wave count: c0 4 waves, c1 3, c2 1 -> 3200 reads/phase (-42%).
// Weight loads: 64B contiguous per lane (4 quads, one base). pa writes are
// ds_write_b128. Block 768 threads; fc head on wave 11. Depth-4 ping-pong
// kept (LDS caps us at 1 WG/CU, so VGPR headroom is free up to ~170).
// Per-column k-order identical to R5 -> bit-identical numerics.
// ---------------------------------------------------------------------------

namespace {
constexpr int kBatch = 1024;
constexpr int kT     = 256;
constexpr int kDIN   = 128;
constexpr int kUNITS = 512;
constexpr int kINTER = 269;
constexpr int kCMD   = 179;
constexpr int kMOTOR = 64;
constexpr int kOUT   = 64;

constexpr int kCAT0 = kDIN + kINTER;    // 397
constexpr int kCAT1 = kINTER + kCMD;    // 448
constexpr int kCAT2 = kCMD + kMOTOR;    // 243

// real combined col counts (ff1 | ff2 | ta+tb)
constexpr int kC0r = 3 * kINTER;  // 807
constexpr int kC1r = 3 * kCMD;    // 537
constexpr int kC2r = 3 * kMOTOR;  // 192
// padded col counts, divisible by 4 (thread owns 4 contiguous cols)
constexpr int kC0p = 808;
constexpr int kC1p = 540;
constexpr int kC2p = 192;
// threads per cell (= colp/4)
constexpr int kP0 = 202;
constexpr int kP1 = 135;
constexpr int kP2 = 48;
// k4 depths padded to multiples of 4 (depth-4 ping-pong) ; LDS a-strides
constexpr int kK40 = 100;               // 397 -> 400
constexpr int kK41 = 112;               // 448 exact
constexpr int kK42 = 64;                // 243 -> 256
constexpr int kS0 = kK40 * 4;           // 400
constexpr int kS1 = kK41 * 4;           // 448
constexpr int kS2 = kK42 * 4;           // 256

constexpr int kQ0 = kK40 * kC0p;        // 80800 float4 quads
constexpr int kQ1 = kK41 * kC1p;        // 60480
constexpr int kQ2 = kK42 * kC2p;        // 12288
constexpr int kQ  = kQ0 + kQ1 + kQ2;    // 153568
constexpr int kBCN = kC0p + kC1p + kC2p;  // 1540 fused biases (padded coords)
constexpr int kBCOff = kQ * 4;          // float offset of biases in ws

constexpr int kMT = 4;     // batch rows per WG
constexpr int kNT = 768;   // threads per WG (12 waves)

static_assert(kK40 % 4 == 0 && kK41 % 4 == 0 && kK42 % 4 == 0, "ping-pong");
static_assert(kC0p % 4 == 0 && kC1p % 4 == 0 && kC2p % 4 == 0, "4-col");
}  // namespace

// Mask element-width detection. mask0 row 0, columns 128..396 are the
// structurally all-true h-block (full = concat([m, ones(n_h,n_h)]) then .T).
__device__ __forceinline__ int detect_mask_mode(const void* m0) {
  const unsigned int* w = (const unsigned int*)m0;
  if (w[32] == 0x01010101u && w[33] == 0x01010101u &&
      w[34] == 0x01010101u && w[35] == 0x01010101u)
    return 0;  // uint8
  if (w[128] == 0x3F800000u && w[129] == 0x3F800000u && w[130] == 0x3F800000u)
    return 2;  // f32
  return 1;    // int32
}

__device__ __forceinline__ bool mask_at(const void* mk, int idx, int mode) {
  if (mode == 0) return ((const unsigned char*)mk)[idx] != 0;
  if (mode == 1) return ((const int*)mk)[idx] != 0;
  return ((const float*)mk)[idx] != 0.0f;
}

// ---------------------------------------------------------------------------
// Prep: packed masked/fused weights, layout W[cell][k4][col_padded][4].
// Pad cols/k-rows are exact zeros (so they contribute 0 to accumulators).
// ---------------------------------------------------------------------------
__global__ void prep_kernel(
    const void* __restrict__ m0_, const void* __restrict__ m1_,
    const void* __restrict__ m2_,
    const float* __restrict__ f1w0, const float* __restrict__ f2w0,
    const float* __restrict__ taw0, const float* __restrict__ tbw0,
    const float* __restrict__ f1w1, const float* __restrict__ f2w1,
    const float* __restrict__ taw1, const float* __restrict__ tbw1,
    const float* __restrict__ f1w2, const float* __restrict__ f2w2,
    const float* __restrict__ taw2, const float* __restrict__ tbw2,
    const float* __restrict__ f1b0, const float* __restrict__ f2b0,
    const float* __restrict__ tab0, const float* __restrict__ tbb0,
    const float* __restrict__ f1b1, const float* __restrict__ f2b1,
    const float* __restrict__ tab1, const float* __restrict__ tbb1,
    const float* __restrict__ f1b2, const float* __restrict__ f2b2,
    const float* __restrict__ tab2, const float* __restrict__ tbb2,
    float* __restrict__ ws) {
  int i = blockIdx.x * 256 + threadIdx.x;
  const int mode = detect_mask_mode(m0_);
  if (i < kQ) {
    int qi, NCp, ncols, cat, nh, baseq;
    const void* mk;
    const float *wf1, *wf2, *wta, *wtb;
    if (i < kQ0) {
      qi = i; NCp = kC0p; ncols = kC0r; cat = kCAT0; nh = kINTER; mk = m0_;
      wf1 = f1w0; wf2 = f2w0; wta = taw0; wtb = tbw0; baseq = 0;
    } else if (i < kQ0 + kQ1) {
      qi = i - kQ0; NCp = kC1p; ncols = kC1r; cat = kCAT1; nh = kCMD; mk = m1_;
      wf1 = f1w1; wf2 = f2w1; wta = taw1; wtb = tbw1; baseq = kQ0;
    } else {
      qi = i - kQ0 - kQ1; NCp = kC2p; ncols = kC2r; cat = kCAT2; nh = kMOTOR;
      mk = m2_;
      wf1 = f1w2; wf2 = f2w2; wta = taw2; wtb = tbw2; baseq = kQ0 + kQ1;
    }
    int k4 = qi / NCp;
    int j  = qi % NCp;
    float v[4] = {0.0f, 0.0f, 0.0f, 0.0f};
    if (j < ncols) {
#pragma unroll
      for (int kk = 0; kk < 4; ++kk) {
        int k = k4 * 4 + kk;
        float r = 0.0f;
        if (k < cat) {
          if (j < nh) {
            r = mask_at(mk, j * cat + k, mode) ? wf1[j * cat + k] : 0.0f;
          } else if (j < 2 * nh) {
            int jj = j - nh;
            r = mask_at(mk, jj * cat + k, mode) ? wf2[jj * cat + k] : 0.0f;
          } else {
            int jj = j - 2 * nh;
            r = wta[jj * cat + k] + wtb[jj * cat + k];
          }
        }
        v[kk] = r;
      }
    }
    ((float4*)ws)[baseq + qi] = make_float4(v[0], v[1], v[2], v[3]);
  } else if (i < kQ + kBCN) {
    int pos = i - kQ;
    int j = pos;
    int nh, ncols;
    const float *bf1, *bf2, *bta, *btb;
    if (j < kC0p) {
      nh = kINTER; ncols = kC0r;
      bf1 = f1b0; bf2 = f2b0; bta = tab0; btb = tbb0;
    } else if (j < kC0p + kC1p) {
      j -= kC0p; nh = kCMD; ncols = kC1r;
      bf1 = f1b1; bf2 = f2b1; bta = tab1; btb = tbb1;
    } else {
      j -= kC0p + kC1p; nh = kMOTOR; ncols = kC2r;
      bf1 = f1b2; bf2 = f2b2; bta = tab2; btb = tbb2;
    }
    float r = 0.0f;
    if (j < ncols) {
      if (j < nh) r = bf1[j];
      else if (j < 2 * nh) r = bf2[j - nh];
      else r = bta[j - 2 * nh] + btb[j - 2 * nh];
    }
    ws[kBCOff + pos] = r;
  }
}

// ---------------------------------------------------------------------------
// 16 FMAs per activation quad: one broadcast ds_read_b128 feeds FOUR columns.
// ---------------------------------------------------------------------------
template <int AST>
__device__ __forceinline__ void fma4(const float4 (&w)[4],
                                     const float* __restrict__ ak,
                                     float (&acc)[4][kMT]) {
#pragma unroll
  for (int r = 0; r < kMT; ++r) {
    float4 av = *(const float4*)(ak + r * AST);
#pragma unroll
    for (int c = 0; c < 4; ++c) {
      acc[c][r] = fmaf(w[c].x, av.x, acc[c][r]);
      acc[c][r] = fmaf(w[c].y, av.y, acc[c][r]);
      acc[c][r] = fmaf(w[c].z, av.z, acc[c][r]);
      acc[c][r] = fmaf(w[c].w, av.w, acc[c][r]);
    }
  }
}

// Four CONTIGUOUS columns (4jq..4jq+3) x kMT rows. Depth-4 ping-pong: sets
// U0/U1/V0/V1 hold 4 k-rows x 4 cols; prefetch of rows k4+4..k4+7 overlaps
// FMAs on k4..k4+3 (>=256 cyc cover for the L2 weight stream). Each weight
// load set is a 64B contiguous chunk per lane -> coalesced dwordx4 x4.
// Bias folded into accumulator init. Per-column k-order identical to R5.
template <int NK4, int NCOLS, int AST, int PST>
__device__ __forceinline__ void mv4(const float4* __restrict__ wp,
                                    const float* __restrict__ a,
                                    float* __restrict__ pc,
                                    const float* __restrict__ bias,
                                    int jq) {
  const float4* pw = wp + 4 * jq;
  float acc[4][kMT];
#pragma unroll
  for (int c = 0; c < 4; ++c) {
    const float b = bias[4 * jq + c];
#pragma unroll
    for (int r = 0; r < kMT; ++r) acc[c][r] = b;
  }
  float4 U0[4], U1[4], V0[4], V1[4];
#pragma unroll
  for (int c = 0; c < 4; ++c) {
    U0[c] = pw[0 * NCOLS + c];
    U1[c] = pw[1 * NCOLS + c];
    V0[c] = pw[2 * NCOLS + c];
    V1[c] = pw[3 * NCOLS + c];
  }
  const float* ak = a;
#pragma unroll 1
  for (int k4 = 0; k4 + 8 <= NK4; k4 += 4) {
    fma4<AST>(U0, ak, acc);
    fma4<AST>(U1, ak + 4, acc);
#pragma unroll
    for (int c = 0; c < 4; ++c) {
      U0[c] = pw[(k4 + 4) * NCOLS + c];
      U1[c] = pw[(k4 + 5) * NCOLS + c];
    }
    fma4<AST>(V0, ak + 8, acc);
    fma4<AST>(V1, ak + 12, acc);
#pragma unroll
    for (int c = 0; c < 4; ++c) {
      V0[c] = pw[(k4 + 6) * NCOLS + c];
      V1[c] = pw[(k4 + 7) * NCOLS + c];
    }
    ak += 16;
  }
  // tail: last 4 k-rows already resident in the ping-pong sets
  fma4<AST>(U0, ak, acc);
  fma4<AST>(U1, ak + 4, acc);
  fma4<AST>(V0, ak + 8, acc);
  fma4<AST>(V1, ak + 12, acc);
#pragma unroll
  for (int r = 0; r < kMT; ++r) {
    float4 o = make_float4(acc[0][r], acc[1][r], acc[2][r], acc[3][r]);
    *(float4*)&pc[r * PST + 4 * jq] = o;  // 16B-aligned: PST%4==0, 4jq quads
  }
}

__device__ __forceinline__ float cfc_combine(float p1, float p2, float pt) {
  float f1 = tanhf(p1);
  float f2 = tanhf(p2);
  float ti = 1.0f / (1.0f + expf(-pt));
  return f1 + ti * (f2 - f1);
}

// ---------------------------------------------------------------------------
// Pipelined persistent kernel. Phase p runs matvecs c0@t=p, c1@t=p-1,
// c2@t=p-2 plus the fc head for t=p-3, then all combines + x prefetch.
// Matvec wave map: waves 0-3 c0, 4-6 c1, 7 c2, 11 fc head.
// Combine map: [0,269) c0, [320,499) c1, [512,576) c2, [576,704) x-prefetch.
// ---------------------------------------------------------------------------
__global__ __launch_bounds__(kNT) void ncp_main(
    const float* __restrict__ x, const float* __restrict__ hidden,
    const float* __restrict__ ws, const float* __restrict__ fcw,
    const float* __restrict__ fcb, float* __restrict__ out) {
  __shared__ __align__(16) float xc0[kMT][kS0];   // [x_t | h0 | pad]
  __shared__ __align__(16) float xc1[kMT][kS1];   // [n0  | h1]
  __shared__ __align__(16) float xc2[kMT][kS2];   // [n1  | h2 | pad]
  __shared__ __align__(16) float pa0[kMT][kC0p];  // pre-act cell0
  __shared__ __align__(16) float pa1[kMT][kC1p];  // pre-act cell1
  __shared__ __align__(16) float pa2[kMT][kC2p];  // pre-act cell2
  __shared__ float s_fcwT[64 * 64];               // fc_w transposed [m][o]
  __shared__ float s_bc[kBCN];
  __shared__ float s_fcb[64];

  const int tid = threadIdx.x;
  const int b0 = blockIdx.x * kMT;

  // zero xc (k-padding lanes must be 0.0f, not garbage: 0*NaN = NaN)
#pragma unroll
  for (int r = 0; r < kMT; ++r) {
    if (tid < kS0) xc0[r][tid] = 0.0f;
    if (tid < kS1) xc1[r][tid] = 0.0f;
    if (tid < kS2) xc2[r][tid] = 0.0f;
  }
  __syncthreads();
  // initial hidden state -> h slots
  for (int i = tid; i < kMT * kUNITS; i += kNT) {
    int r = i >> 9, u = i & 511;
    float v = hidden[(size_t)(b0 + r) * kUNITS + u];
    if (u < kINTER) xc0[r][kDIN + u] = v;
    else if (u < kINTER + kCMD) xc1[r][u] = v;  // layout offset == u
    else xc2[r][kCMD + (u - (kINTER + kCMD))] = v;
  }
  for (int i = tid; i < kBCN; i += kNT) s_bc[i] = ws[kBCOff + i];
  if (tid < 64) s_fcb[tid] = fcb[tid];
  for (int i = tid; i < 64 * 64; i += kNT) {
    int m = i >> 6, o = i & 63;
    s_fcwT[i] = fcw[o * 64 + m];
  }
  if (tid < 128) {  // stage x(0): 4 rows x 128 floats = 128 float4
    int r = tid >> 5, d4 = tid & 31;
    *(float4*)&xc0[r][d4 * 4] =
        *(const float4*)&x[(size_t)(b0 + r) * (kT * kDIN) + d4 * 4];
  }
  __syncthreads();

  const float4* wp0 = (const float4*)ws;
  const float4* wp1 = wp0 + kQ0;
  const float4* wp2 = wp1 + kQ1;

  for (int p = 0; p < kT + 3; ++p) {
    // ================= matvec + fc section =================
    if (tid < 256) {
      if (p < kT && tid < kP0)
        mv4<kK40, kC0p, kS0, kC0p>(wp0, &xc0[0][0], &pa0[0][0], s_bc, tid);
    } else if (tid < 448) {
      const int pi = tid - 256;
      if (p >= 1 && p <= kT && pi < kP1)
        mv4<kK41, kC1p, kS1, kC1p>(wp1, &xc1[0][0], &pa1[0][0], s_bc + kC0p,
                                   pi);
    } else if (tid < 512) {
      const int pi = tid - 448;
      if (p >= 2 && p <= kT + 1 && pi < kP2)
        mv4<kK42, kC2p, kS2, kC2p>(wp2, &xc2[0][0], &pa2[0][0],
                                   s_bc + kC0p + kC1p, pi);
    } else if (tid >= 704) {
      // wave 11: fc head for t = p-3; reads n2(t) left in xc2 by comb2@p-1.
      if (p >= 3) {
        const int o = tid - 704;  // 0..63
        const int t_fc = p - 3;
        float a0 = s_fcb[o], a1 = a0, a2 = a0, a3 = a0;
        for (int m = 0; m < kMOTOR; ++m) {
          float w = s_fcwT[m * 64 + o];
          a0 = fmaf(xc2[0][kCMD + m], w, a0);
          a1 = fmaf(xc2[1][kCMD + m], w, a1);
          a2 = fmaf(xc2[2][kCMD + m], w, a2);
          a3 = fmaf(xc2[3][kCMD + m], w, a3);
        }
        size_t base =
            (size_t)b0 * (kT * kOUT) + (size_t)t_fc * kOUT + o;
        const size_t rstride = (size_t)kT * kOUT;
        out[base] = a0;
        out[base + rstride] = a1;
        out[base + 2 * rstride] = a2;
        out[base + 3 * rstride] = a3;
      }
    }
    __syncthreads();
    // ================= combine + stage section =================
    if (tid < kINTER) {
      if (p < kT) {
#pragma unroll
        for (int r = 0; r < kMT; ++r) {
          float v = cfc_combine(pa0[r][tid], pa0[r][tid + kINTER],
                                pa0[r][tid + 2 * kINTER]);
          xc1[r][tid] = v;          // input to c1 (next phase)
          xc0[r][kDIN + tid] = v;   // h0 for c0@p+1
        }
      }
    } else if (tid >= 320 && tid < 320 + kCMD) {
      if (p >= 1 && p <= kT) {
        const int j = tid - 320;
#pragma unroll
        for (int r = 0; r < kMT; ++r) {
          float v = cfc_combine(pa1[r][j], pa1[r][j + kCMD],
                                pa1[r][j + 2 * kCMD]);
          xc2[r][j] = v;            // input to c2 (next phase)
          xc1[r][kINTER + j] = v;   // h1
        }
      }
    } else if (tid >= 512 && tid < 512 + kMOTOR) {
      if (p >= 2 && p <= kT + 1) {
        const int j = tid - 512;
#pragma unroll
        for (int r = 0; r < kMT; ++r) {
          float v = cfc_combine(pa2[r][j], pa2[r][j + kMOTOR],
                                pa2[r][j + 2 * kMOTOR]);
          xc2[r][kCMD + j] = v;     // h2 == n2(t) -> fc head @p+1
        }
      }
    } else if (tid >= 576 && tid < 704) {
      if (p + 1 < kT) {  // prefetch x(p+1) for next phase's c0
        const int i2 = tid - 576;
        const int r = i2 >> 5, d4 = i2 & 31;
        *(float4*)&xc0[r][d4 * 4] =
            *(const float4*)&x[(size_t)(b0 + r) * (kT * kDIN) +
                               (size_t)(p + 1) * kDIN + d4 * 4];
      }
    }
    __syncthreads();
  }

  // final hidden state: h0(255)/h1(255)/h2(255) are in the h slots
  const size_t hnoff = (size_t)kBatch * kT * kOUT;
  for (int i = tid; i < kMT * kUNITS; i += kNT) {
    int r = i >> 9, u = i & 511;
    float v;
    if (u < kINTER) v = xc0[r][kDIN + u];
    else if (u < kINTER + kCMD) v = xc1[r][u];
    else v = xc2[r][kCMD + (u - (kINTER + kCMD))];
    out[hnoff + (size_t)(b0 + r) * kUNITS + u] = v;
  }
}

// ---------------------------------------------------------------------------
extern "C" void kernel_launch(void* const* d_in, const int* in_sizes, int n_in,
                              void* d_out, int out_size, void* d_ws, size_t ws_size,
                              hipStream_t stream) {
  (void)in_sizes; (void)n_in; (void)out_size; (void)ws_size;
  const float* x = (const float*)d_in[0];
  const float* hidden = (const float*)d_in[1];
  const void* m0 = d_in[2];
  const void* m1 = d_in[3];
  const void* m2 = d_in[4];
  const float* f1w0 = (const float*)d_in[5];
  const float* f1b0 = (const float*)d_in[6];
  const float* f2w0 = (const float*)d_in[7];
  const float* f2b0 = (const float*)d_in[8];
  const float* taw0 = (const float*)d_in[9];
  const float* tab0 = (const float*)d_in[10];
  const float* tbw0 = (const float*)d_in[11];
  const float* tbb0 = (const float*)d_in[12];
  const float* f1w1 = (const float*)d_in[13];
  const float* f1b1 = (const float*)d_in[14];
  const float* f2w1 = (const float*)d_in[15];
  const float* f2b1 = (const float*)d_in[16];
  const float* taw1 = (const float*)d_in[17];
  const float* tab1 = (const float*)d_in[18];
  const float* tbw1 = (const float*)d_in[19];
  const float* tbb1 = (const float*)d_in[20];
  const float* f1w2 = (const float*)d_in[21];
  const float* f1b2 = (const float*)d_in[22];
  const float* f2w2 = (const float*)d_in[23];
  const float* f2b2 = (const float*)d_in[24];
  const float* taw2 = (const float*)d_in[25];
  const float* tab2 = (const float*)d_in[26];
  const float* tbw2 = (const float*)d_in[27];
  const float* tbb2 = (const float*)d_in[28];
  const float* fcw = (const float*)d_in[29];
  const float* fcb = (const float*)d_in[30];
  float* ws = (float*)d_ws;
  float* out = (float*)d_out;

  const int prep_items = kQ + kBCN;  // 155108
  prep_kernel<<<(prep_items + 255) / 256, 256, 0, stream>>>(
      m0, m1, m2,
      f1w0, f2w0, taw0, tbw0,
      f1w1, f2w1, taw1, tbw1,
      f1w2, f2w2, taw2, tbw2,
      f1b0, f2b0, tab0, tbb0,
      f1b1, f2b1, tab1, tbb1,
      f1b2, f2b2, tab2, tbb2,
      ws);

  ncp_main<<<kBatch / kMT, kNT, 0, stream>>>(x, hidden, ws, fcw, fcb, out);
}

// Round 4
// 8415.648 us; speedup vs baseline: 1.3090x; 1.3090x over previous
//
#include <hip/hip_runtime.h>
#include <math.h>

// ---------------------------------------------------------------------------
// NCPDecoder: 3-cell CfC RNN, B=1024, T=256.
// Round 6->7: fix the R6 coalescing regression, keep 4-col blocking.
// R6 (11.0 ms bench / 12.1 ms prof, VALUBusy 46%): contiguous 4-col-per-
// thread made every weight-load instruction 64B-lane-strided -> 64 cache
// lines/instr (4x R5's 16) -> ~154k line-requests/phase/CU on the TA/TCP
// path ~= 64 us; waves sat on vmcnt (VALUBusy 76->46).
// R7: thread owns STRIDED columns {j, j+P, j+2P, j+3P}, P=NCOLS/4, on the
// natural [k4][col] weight layout (same as R5; prep unchanged). Each of the
// 4 load instrs is 16B-lane-stride -> fully coalesced, 38.4k line-req/phase
// (=R5) while keeping R6's 3200 ds_read_b128/phase (-42% vs R5).
// Per-phase: LDS ~16us | VMEM-req ~16us | worst-SIMD VALU ~11us, on three
// different pipes. pa written as 16 lane-contiguous ds_write_b32/thread.
// Per-column k-order and bias init unchanged -> identical numerics.
// ---------------------------------------------------------------------------

namespace {
constexpr int kBatch = 1024;
constexpr int kT     = 256;
constexpr int kDIN   = 128;
constexpr int kUNITS = 512;
constexpr int kINTER = 269;
constexpr int kCMD   = 179;
constexpr int kMOTOR = 64;
constexpr int kOUT   = 64;

constexpr int kCAT0 = kDIN + kINTER;    // 397
constexpr int kCAT1 = kINTER + kCMD;    // 448
constexpr int kCAT2 = kCMD + kMOTOR;    // 243

// real combined col counts (ff1 | ff2 | ta+tb)
constexpr int kC0r = 3 * kINTER;  // 807
constexpr int kC1r = 3 * kCMD;    // 537
constexpr int kC2r = 3 * kMOTOR;  // 192
// padded col counts, divisible by 4 (thread owns 4 strided cols)
constexpr int kC0p = 808;
constexpr int kC1p = 540;
constexpr int kC2p = 192;
// threads per cell (= colp/4)
constexpr int kP0 = 202;
constexpr int kP1 = 135;
constexpr int kP2 = 48;
// k4 depths padded to multiples of 4 (depth-4 ping-pong) ; LDS a-strides
constexpr int kK40 = 100;               // 397 -> 400
constexpr int kK41 = 112;               // 448 exact
constexpr int kK42 = 64;                // 243 -> 256
constexpr int kS0 = kK40 * 4;           // 400
constexpr int kS1 = kK41 * 4;           // 448
constexpr int kS2 = kK42 * 4;           // 256

constexpr int kQ0 = kK40 * kC0p;        // 80800 float4 quads
constexpr int kQ1 = kK41 * kC1p;        // 60480
constexpr int kQ2 = kK42 * kC2p;        // 12288
constexpr int kQ  = kQ0 + kQ1 + kQ2;    // 153568
constexpr int kBCN = kC0p + kC1p + kC2p;  // 1540 fused biases (padded coords)
constexpr int kBCOff = kQ * 4;          // float offset of biases in ws

constexpr int kMT = 4;     // batch rows per WG
constexpr int kNT = 768;   // threads per WG (12 waves)

static_assert(kK40 % 4 == 0 && kK41 % 4 == 0 && kK42 % 4 == 0, "ping-pong");
static_assert(kC0p % 4 == 0 && kC1p % 4 == 0 && kC2p % 4 == 0, "4-col");
}  // namespace

// Mask element-width detection. mask0 row 0, columns 128..396 are the
// structurally all-true h-block (full = concat([m, ones(n_h,n_h)]) then .T).
__device__ __forceinline__ int detect_mask_mode(const void* m0) {
  const unsigned int* w = (const unsigned int*)m0;
  if (w[32] == 0x01010101u && w[33] == 0x01010101u &&
      w[34] == 0x01010101u && w[35] == 0x01010101u)
    return 0;  // uint8
  if (w[128] == 0x3F800000u && w[129] == 0x3F800000u && w[130] == 0x3F800000u)
    return 2;  // f32
  return 1;    // int32
}

__device__ __forceinline__ bool mask_at(const void* mk, int idx, int mode) {
  if (mode == 0) return ((const unsigned char*)mk)[idx] != 0;
  if (mode == 1) return ((const int*)mk)[idx] != 0;
  return ((const float*)mk)[idx] != 0.0f;
}

// ---------------------------------------------------------------------------
// Prep: packed masked/fused weights, layout W[cell][k4][col_padded][4].
// Pad cols/k-rows are exact zeros (so they contribute 0 to accumulators).
// ---------------------------------------------------------------------------
__global__ void prep_kernel(
    const void* __restrict__ m0_, const void* __restrict__ m1_,
    const void* __restrict__ m2_,
    const float* __restrict__ f1w0, const float* __restrict__ f2w0,
    const float* __restrict__ taw0, const float* __restrict__ tbw0,
    const float* __restrict__ f1w1, const float* __restrict__ f2w1,
    const float* __restrict__ taw1, const float* __restrict__ tbw1,
    const float* __restrict__ f1w2, const float* __restrict__ f2w2,
    const float* __restrict__ taw2, const float* __restrict__ tbw2,
    const float* __restrict__ f1b0, const float* __restrict__ f2b0,
    const float* __restrict__ tab0, const float* __restrict__ tbb0,
    const float* __restrict__ f1b1, const float* __restrict__ f2b1,
    const float* __restrict__ tab1, const float* __restrict__ tbb1,
    const float* __restrict__ f1b2, const float* __restrict__ f2b2,
    const float* __restrict__ tab2, const float* __restrict__ tbb2,
    float* __restrict__ ws) {
  int i = blockIdx.x * 256 + threadIdx.x;
  const int mode = detect_mask_mode(m0_);
  if (i < kQ) {
    int qi, NCp, ncols, cat, nh, baseq;
    const void* mk;
    const float *wf1, *wf2, *wta, *wtb;
    if (i < kQ0) {
      qi = i; NCp = kC0p; ncols = kC0r; cat = kCAT0; nh = kINTER; mk = m0_;
      wf1 = f1w0; wf2 = f2w0; wta = taw0; wtb = tbw0; baseq = 0;
    } else if (i < kQ0 + kQ1) {
      qi = i - kQ0; NCp = kC1p; ncols = kC1r; cat = kCAT1; nh = kCMD; mk = m1_;
      wf1 = f1w1; wf2 = f2w1; wta = taw1; wtb = tbw1; baseq = kQ0;
    } else {
      qi = i - kQ0 - kQ1; NCp = kC2p; ncols = kC2r; cat = kCAT2; nh = kMOTOR;
      mk = m2_;
      wf1 = f1w2; wf2 = f2w2; wta = taw2; wtb = tbw2; baseq = kQ0 + kQ1;
    }
    int k4 = qi / NCp;
    int j  = qi % NCp;
    float v[4] = {0.0f, 0.0f, 0.0f, 0.0f};
    if (j < ncols) {
#pragma unroll
      for (int kk = 0; kk < 4; ++kk) {
        int k = k4 * 4 + kk;
        float r = 0.0f;
        if (k < cat) {
          if (j < nh) {
            r = mask_at(mk, j * cat + k, mode) ? wf1[j * cat + k] : 0.0f;
          } else if (j < 2 * nh) {
            int jj = j - nh;
            r = mask_at(mk, jj * cat + k, mode) ? wf2[jj * cat + k] : 0.0f;
          } else {
            int jj = j - 2 * nh;
            r = wta[jj * cat + k] + wtb[jj * cat + k];
          }
        }
        v[kk] = r;
      }
    }
    ((float4*)ws)[baseq + qi] = make_float4(v[0], v[1], v[2], v[3]);
  } else if (i < kQ + kBCN) {
    int pos = i - kQ;
    int j = pos;
    int nh, ncols;
    const float *bf1, *bf2, *bta, *btb;
    if (j < kC0p) {
      nh = kINTER; ncols = kC0r;
      bf1 = f1b0; bf2 = f2b0; bta = tab0; btb = tbb0;
    } else if (j < kC0p + kC1p) {
      j -= kC0p; nh = kCMD; ncols = kC1r;
      bf1 = f1b1; bf2 = f2b1; bta = tab1; btb = tbb1;
    } else {
      j -= kC0p + kC1p; nh = kMOTOR; ncols = kC2r;
      bf1 = f1b2; bf2 = f2b2; bta = tab2; btb = tbb2;
    }
    float r = 0.0f;
    if (j < ncols) {
      if (j < nh) r = bf1[j];
      else if (j < 2 * nh) r = bf2[j - nh];
      else r = bta[j - 2 * nh] + btb[j - 2 * nh];
    }
    ws[kBCOff + pos] = r;
  }
}

// ---------------------------------------------------------------------------
// 16 FMAs per activation quad: one broadcast ds_read_b128 feeds FOUR columns.
// ---------------------------------------------------------------------------
template <int AST>
__device__ __forceinline__ void fma4(const float4 (&w)[4],
                                     const float* __restrict__ ak,
                                     float (&acc)[4][kMT]) {
#pragma unroll
  for (int r = 0; r < kMT; ++r) {
    float4 av = *(const float4*)(ak + r * AST);
#pragma unroll
    for (int c = 0; c < 4; ++c) {
      acc[c][r] = fmaf(w[c].x, av.x, acc[c][r]);
      acc[c][r] = fmaf(w[c].y, av.y, acc[c][r]);
      acc[c][r] = fmaf(w[c].z, av.z, acc[c][r]);
      acc[c][r] = fmaf(w[c].w, av.w, acc[c][r]);
    }
  }
}

// Four STRIDED columns {j, j+P, j+2P, j+3P}, P=NCOLS/4, x kMT rows.
// Natural [k4][col] weight layout: each of the 4 per-k4 load instructions is
// 16B-lane-strided -> fully coalesced (16 cache lines/instr). Depth-4
// ping-pong: U0/U1/V0/V1 hold 4 k-rows x 4 cols; prefetch of k4+4..k4+7
// overlaps FMAs on k4..k4+3. Bias folded into accumulator init.
template <int NK4, int NCOLS, int AST, int PST>
__device__ __forceinline__ void mv4(const float4* __restrict__ wp,
                                    const float* __restrict__ a,
                                    float* __restrict__ pc,
                                    const float* __restrict__ bias,
                                    int j) {
  constexpr int P = NCOLS / 4;
  const float4* pw = wp + j;
  float acc[4][kMT];
#pragma unroll
  for (int c = 0; c < 4; ++c) {
    const float b = bias[c * P + j];
#pragma unroll
    for (int r = 0; r < kMT; ++r) acc[c][r] = b;
  }
  float4 U0[4], U1[4], V0[4], V1[4];
#pragma unroll
  for (int c = 0; c < 4; ++c) {
    U0[c] = pw[0 * NCOLS + c * P];
    U1[c] = pw[1 * NCOLS + c * P];
    V0[c] = pw[2 * NCOLS + c * P];
    V1[c] = pw[3 * NCOLS + c * P];
  }
  const float* ak = a;
#pragma unroll 1
  for (int k4 = 0; k4 + 8 <= NK4; k4 += 4) {
    fma4<AST>(U0, ak, acc);
    fma4<AST>(U1, ak + 4, acc);
#pragma unroll
    for (int c = 0; c < 4; ++c) {
      U0[c] = pw[(k4 + 4) * NCOLS + c * P];
      U1[c] = pw[(k4 + 5) * NCOLS + c * P];
    }
    fma4<AST>(V0, ak + 8, acc);
    fma4<AST>(V1, ak + 12, acc);
#pragma unroll
    for (int c = 0; c < 4; ++c) {
      V0[c] = pw[(k4 + 6) * NCOLS + c * P];
      V1[c] = pw[(k4 + 7) * NCOLS + c * P];
    }
    ak += 16;
  }
  // tail: last 4 k-rows already resident in the ping-pong sets
  fma4<AST>(U0, ak, acc);
  fma4<AST>(U1, ak + 4, acc);
  fma4<AST>(V0, ak + 8, acc);
  fma4<AST>(V1, ak + 12, acc);
  // 16 lane-contiguous ds_write_b32 (conflict-free; trivial wave count)
#pragma unroll
  for (int r = 0; r < kMT; ++r)
#pragma unroll
    for (int c = 0; c < 4; ++c) pc[r * PST + c * P + j] = acc[c][r];
}

__device__ __forceinline__ float cfc_combine(float p1, float p2, float pt) {
  float f1 = tanhf(p1);
  float f2 = tanhf(p2);
  float ti = 1.0f / (1.0f + expf(-pt));
  return f1 + ti * (f2 - f1);
}

// ---------------------------------------------------------------------------
// Pipelined persistent kernel. Phase p runs matvecs c0@t=p, c1@t=p-1,
// c2@t=p-2 plus the fc head for t=p-3, then all combines + x prefetch.
// Matvec wave map: waves 0-3 c0, 4-6 c1, 7 c2, 11 fc head.
// Combine map: [0,269) c0, [320,499) c1, [512,576) c2, [576,704) x-prefetch.
// ---------------------------------------------------------------------------
__global__ __launch_bounds__(kNT) void ncp_main(
    const float* __restrict__ x, const float* __restrict__ hidden,
    const float* __restrict__ ws, const float* __restrict__ fcw,
    const float* __restrict__ fcb, float* __restrict__ out) {
  __shared__ __align__(16) float xc0[kMT][kS0];   // [x_t | h0 | pad]
  __shared__ __align__(16) float xc1[kMT][kS1];   // [n0  | h1]
  __shared__ __align__(16) float xc2[kMT][kS2];   // [n1  | h2 | pad]
  __shared__ __align__(16) float pa0[kMT][kC0p];  // pre-act cell0
  __shared__ __align__(16) float pa1[kMT][kC1p];  // pre-act cell1
  __shared__ __align__(16) float pa2[kMT][kC2p];  // pre-act cell2
  __shared__ float s_fcwT[64 * 64];               // fc_w transposed [m][o]
  __shared__ float s_bc[kBCN];
  __shared__ float s_fcb[64];

  const int tid = threadIdx.x;
  const int b0 = blockIdx.x * kMT;

  // zero xc (k-padding lanes must be 0.0f, not garbage: 0*NaN = NaN)
#pragma unroll
  for (int r = 0; r < kMT; ++r) {
    if (tid < kS0) xc0[r][tid] = 0.0f;
    if (tid < kS1) xc1[r][tid] = 0.0f;
    if (tid < kS2) xc2[r][tid] = 0.0f;
  }
  __syncthreads();
  // initial hidden state -> h slots
  for (int i = tid; i < kMT * kUNITS; i += kNT) {
    int r = i >> 9, u = i & 511;
    float v = hidden[(size_t)(b0 + r) * kUNITS + u];
    if (u < kINTER) xc0[r][kDIN + u] = v;
    else if (u < kINTER + kCMD) xc1[r][u] = v;  // layout offset == u
    else xc2[r][kCMD + (u - (kINTER + kCMD))] = v;
  }
  for (int i = tid; i < kBCN; i += kNT) s_bc[i] = ws[kBCOff + i];
  if (tid < 64) s_fcb[tid] = fcb[tid];
  for (int i = tid; i < 64 * 64; i += kNT) {
    int m = i >> 6, o = i & 63;
    s_fcwT[i] = fcw[o * 64 + m];
  }
  if (tid < 128) {  // stage x(0): 4 rows x 128 floats = 128 float4
    int r = tid >> 5, d4 = tid & 31;
    *(float4*)&xc0[r][d4 * 4] =
        *(const float4*)&x[(size_t)(b0 + r) * (kT * kDIN) + d4 * 4];
  }
  __syncthreads();

  const float4* wp0 = (const float4*)ws;
  const float4* wp1 = wp0 + kQ0;
  const float4* wp2 = wp1 + kQ1;

  for (int p = 0; p < kT + 3; ++p) {
    // ================= matvec + fc section =================
    if (tid < 256) {
      if (p < kT && tid < kP0)
        mv4<kK40, kC0p, kS0, kC0p>(wp0, &xc0[0][0], &pa0[0][0], s_bc, tid);
    } else if (tid < 448) {
      const int pi = tid - 256;
      if (p >= 1 && p <= kT && pi < kP1)
        mv4<kK41, kC1p, kS1, kC1p>(wp1, &xc1[0][0], &pa1[0][0], s_bc + kC0p,
                                   pi);
    } else if (tid < 512) {
      const int pi = tid - 448;
      if (p >= 2 && p <= kT + 1 && pi < kP2)
        mv4<kK42, kC2p, kS2, kC2p>(wp2, &xc2[0][0], &pa2[0][0],
                                   s_bc + kC0p + kC1p, pi);
    } else if (tid >= 704) {
      // wave 11: fc head for t = p-3; reads n2(t) left in xc2 by comb2@p-1.
      if (p >= 3) {
        const int o = tid - 704;  // 0..63
        const int t_fc = p - 3;
        float a0 = s_fcb[o], a1 = a0, a2 = a0, a3 = a0;
        for (int m = 0; m < kMOTOR; ++m) {
          float w = s_fcwT[m * 64 + o];
          a0 = fmaf(xc2[0][kCMD + m], w, a0);
          a1 = fmaf(xc2[1][kCMD + m], w, a1);
          a2 = fmaf(xc2[2][kCMD + m], w, a2);
          a3 = fmaf(xc2[3][kCMD + m], w, a3);
        }
        size_t base =
            (size_t)b0 * (kT * kOUT) + (size_t)t_fc * kOUT + o;
        const size_t rstride = (size_t)kT * kOUT;
        out[base] = a0;
        out[base + rstride] = a1;
        out[base + 2 * rstride] = a2;
        out[base + 3 * rstride] = a3;
      }
    }
    __syncthreads();
    // ================= combine + stage section =================
    if (tid < kINTER) {
      if (p < kT) {
#pragma unroll
        for (int r = 0; r < kMT; ++r) {
          float v = cfc_combine(pa0[r][tid], pa0[r][tid + kINTER],
                                pa0[r][tid + 2 * kINTER]);
          xc1[r][tid] = v;          // input to c1 (next phase)
          xc0[r][kDIN + tid] = v;   // h0 for c0@p+1
        }
      }
    } else if (tid >= 320 && tid < 320 + kCMD) {
      if (p >= 1 && p <= kT) {
        const int j = tid - 320;
#pragma unroll
        for (int r = 0; r < kMT; ++r) {
          float v = cfc_combine(pa1[r][j], pa1[r][j + kCMD],
                                pa1[r][j + 2 * kCMD]);
          xc2[r][j] = v;            // input to c2 (next phase)
          xc1[r][kINTER + j] = v;   // h1
        }
      }
    } else if (tid >= 512 && tid < 512 + kMOTOR) {
      if (p >= 2 && p <= kT + 1) {
        const int j = tid - 512;
#pragma unroll
        for (int r = 0; r < kMT; ++r) {
          float v = cfc_combine(pa2[r][j], pa2[r][j + kMOTOR],
                                pa2[r][j + 2 * kMOTOR]);
          xc2[r][kCMD + j] = v;     // h2 == n2(t) -> fc head @p+1
        }
      }
    } else if (tid >= 576 && tid < 704) {
      if (p + 1 < kT) {  // prefetch x(p+1) for next phase's c0
        const int i2 = tid - 576;
        const int r = i2 >> 5, d4 = i2 & 31;
        *(float4*)&xc0[r][d4 * 4] =
            *(const float4*)&x[(size_t)(b0 + r) * (kT * kDIN) +
                               (size_t)(p + 1) * kDIN + d4 * 4];
      }
    }
    __syncthreads();
  }

  // final hidden state: h0(255)/h1(255)/h2(255) are in the h slots
  const size_t hnoff = (size_t)kBatch * kT * kOUT;
  for (int i = tid; i < kMT * kUNITS; i += kNT) {
    int r = i >> 9, u = i & 511;
    float v;
    if (u < kINTER) v = xc0[r][kDIN + u];
    else if (u < kINTER + kCMD) v = xc1[r][u];
    else v = xc2[r][kCMD + (u - (kINTER + kCMD))];
    out[hnoff + (size_t)(b0 + r) * kUNITS + u] = v;
  }
}

// ---------------------------------------------------------------------------
extern "C" void kernel_launch(void* const* d_in, const int* in_sizes, int n_in,
                              void* d_out, int out_size, void* d_ws, size_t ws_size,
                              hipStream_t stream) {
  (void)in_sizes; (void)n_in; (void)out_size; (void)ws_size;
  const float* x = (const float*)d_in[0];
  const float* hidden = (const float*)d_in[1];
  const void* m0 = d_in[2];
  const void* m1 = d_in[3];
  const void* m2 = d_in[4];
  const float* f1w0 = (const float*)d_in[5];
  const float* f1b0 = (const float*)d_in[6];
  const float* f2w0 = (const float*)d_in[7];
  const float* f2b0 = (const float*)d_in[8];
  const float* taw0 = (const float*)d_in[9];
  const float* tab0 = (const float*)d_in[10];
  const float* tbw0 = (const float*)d_in[11];
  const float* tbb0 = (const float*)d_in[12];
  const float* f1w1 = (const float*)d_in[13];
  const float* f1b1 = (const float*)d_in[14];
  const float* f2w1 = (const float*)d_in[15];
  const float* f2b1 = (const float*)d_in[16];
  const float* taw1 = (const float*)d_in[17];
  const float* tab1 = (const float*)d_in[18];
  const float* tbw1 = (const float*)d_in[19];
  const float* tbb1 = (const float*)d_in[20];
  const float* f1w2 = (const float*)d_in[21];
  const float* f1b2 = (const float*)d_in[22];
  const float* f2w2 = (const float*)d_in[23];
  const float* f2b2 = (const float*)d_in[24];
  const float* taw2 = (const float*)d_in[25];
  const float* tab2 = (const float*)d_in[26];
  const float* tbw2 = (const float*)d_in[27];
  const float* tbb2 = (const float*)d_in[28];
  const float* fcw = (const float*)d_in[29];
  const float* fcb = (const float*)d_in[30];
  float* ws = (float*)d_ws;
  float* out = (float*)d_out;

  const int prep_items = kQ + kBCN;  // 155108
  prep_kernel<<<(prep_items + 255) / 256, 256, 0, stream>>>(
      m0, m1, m2,
      f1w0, f2w0, taw0, tbw0,
      f1w1, f2w1, taw1, tbw1,
      f1w2, f2w2, taw2, tbw2,
      f1b0, f2b0, tab0, tbb0,
      f1b1, f2b1, tab1, tbb1,
      f1b2, f2b2, tab2, tbb2,
      ws);

  ncp_main<<<kBatch / kMT, kNT, 0, stream>>>(x, hidden, ws, fcw, fcb, out);
}